// Round 6
// baseline (1465.832 us; speedup 1.0000x reference)
//
#include <hip/hip_runtime.h>
#include <cstdint>
#include <cstddef>

#define BATCH 16

static constexpr int NN0 = 32768, NN1 = 8192, NN2 = 2048, NN3 = 512, NN4 = 128;

__device__ __forceinline__ float fast_elu(float a) {
    return a > 0.f ? a : __expf(a) - 1.f;
}

// ---------------- fused weight transposes: W (CO,K) -> Wt (K,CO) ----------------
struct TD { const float* W; float* Wt; int CO, K, off; };
struct TA { TD d[8]; int total; };

__global__ __launch_bounds__(256) void transpose_all(TA a) {
    int i = blockIdx.x * 256 + threadIdx.x;
    if (i >= a.total) return;
    #pragma unroll
    for (int j = 0; j < 8; ++j) {
        const TD t = a.d[j];
        if (i >= t.off && i < t.off + t.CO * t.K) {
            int e = i - t.off, c = e / t.K, k = e - c * t.K;
            t.Wt[k * t.CO + c] = t.W[e];
            return;
        }
    }
}

// XCD-pinned swizzle for (GX, BATCH) grids launched as 1D GX*16:
// batch -> XCD (id&7); two sequential halves give batches {xcd, xcd+8}.
// Bijective for any GX (grid GX*16 is always a multiple of 8).
__device__ __forceinline__ void swz_decode(int id, int GX, int& bx, int& b) {
    const int xcd = id & 7;
    const int j   = id >> 3;            // 0 .. 2*GX-1
    const int hf  = (j >= GX) ? 1 : 0;
    bx = j - (hf ? GX : 0);
    b  = xcd + 8 * hf;
}

// ---------------- conv v5: lane=vertex, wave=16ch group, scalar W, reg-prefetch ----
// x: (B,N,CIN), idx: (N,9), Wt: (9*CIN, COUT), out: (B,N,COUT)
template<int CIN, int COUT, bool ELU>
__global__ __launch_bounds__(256) void conv_v5(const float* __restrict__ x,
                                               const int* __restrict__ idx,
                                               const float* __restrict__ Wt,
                                               const float* __restrict__ bias,
                                               float* __restrict__ out,
                                               int N, int GX) {
    static_assert(COUT % 16 == 0, "COUT multiple of 16");
    constexpr int QG    = COUT / 16;
    static_assert(QG <= 4 && 4 % QG == 0, "QG in {1,2,4}");
    constexpr int VSETS = 4 / QG;
    constexpr int VPB   = 64 * VSETS;
    constexpr int GS    = CIN + 4;      // stride %32 banks == 4 -> conflict-free b128
    constexpr int CQ    = CIN / 4;
    constexpr int GP    = (VPB * CQ) / 256;   // staging float4 regs per thread
    static_assert((VPB * CQ) % 256 == 0, "staging divisibility");

    __shared__ float g[VPB][GS];
    __shared__ int   nbr[VPB][9];

    int bx, b;
    swz_decode(blockIdx.x, GX, bx, b);
    const int v0 = bx * VPB;
    const float* __restrict__ xb = x + (size_t)b * N * CIN;

    for (int t = threadIdx.x; t < VPB * 9; t += 256)
        nbr[t / 9][t % 9] = idx[(size_t)v0 * 9 + t];
    __syncthreads();

    const int wv   = __builtin_amdgcn_readfirstlane(threadIdx.x >> 6);
    const int lane = threadIdx.x & 63;
    const int vset = wv / QG;
    const int qg   = wv % QG;
    const int vloc = vset * 64 + lane;

    float4 r[GP];
    auto issue_loads = [&](int s) {
        #pragma unroll
        for (int p = 0; p < GP; ++p) {
            const int slot = p * 256 + threadIdx.x;
            const int v = slot / CQ, q = slot - v * CQ;
            r[p] = *reinterpret_cast<const float4*>(
                xb + (size_t)nbr[v][s] * CIN + q * 4);
        }
    };
    auto write_lds = [&]() {
        #pragma unroll
        for (int p = 0; p < GP; ++p) {
            const int slot = p * 256 + threadIdx.x;
            const int v = slot / CQ, q = slot - v * CQ;
            *reinterpret_cast<float4*>(&g[v][q * 4]) = r[p];
        }
    };

    float4 acc[4];
    #pragma unroll
    for (int q = 0; q < 4; ++q) acc[q] = make_float4(0.f, 0.f, 0.f, 0.f);

    issue_loads(0);
    write_lds();
    __syncthreads();

    for (int s = 0; s < 9; ++s) {
        if (s < 8) issue_loads(s + 1);      // in flight during compute
        const float* __restrict__ wbase = Wt + (size_t)s * CIN * COUT + qg * 16;
        #pragma unroll
        for (int k4 = 0; k4 < CQ; ++k4) {
            const float4 gv = *reinterpret_cast<const float4*>(&g[vloc][k4 * 4]);
            #pragma unroll
            for (int kk = 0; kk < 4; ++kk) {
                const float* __restrict__ wr = wbase + (size_t)(k4 * 4 + kk) * COUT;
                const float4 w0 = *reinterpret_cast<const float4*>(wr);
                const float4 w1 = *reinterpret_cast<const float4*>(wr + 4);
                const float4 w2 = *reinterpret_cast<const float4*>(wr + 8);
                const float4 w3 = *reinterpret_cast<const float4*>(wr + 12);
                const float gk = (kk == 0) ? gv.x : (kk == 1) ? gv.y : (kk == 2) ? gv.z : gv.w;
                acc[0].x += gk * w0.x; acc[0].y += gk * w0.y; acc[0].z += gk * w0.z; acc[0].w += gk * w0.w;
                acc[1].x += gk * w1.x; acc[1].y += gk * w1.y; acc[1].z += gk * w1.z; acc[1].w += gk * w1.w;
                acc[2].x += gk * w2.x; acc[2].y += gk * w2.y; acc[2].z += gk * w2.z; acc[2].w += gk * w2.w;
                acc[3].x += gk * w3.x; acc[3].y += gk * w3.y; acc[3].z += gk * w3.z; acc[3].w += gk * w3.w;
            }
        }
        __syncthreads();                    // all reads of g done
        if (s < 8) { write_lds(); __syncthreads(); }   // vmcnt wait lands here, post-compute
    }

    float* __restrict__ orow = out + ((size_t)b * N + v0 + vloc) * COUT + qg * 16;
    #pragma unroll
    for (int q = 0; q < 4; ++q) {
        const float4 bv = *reinterpret_cast<const float4*>(bias + qg * 16 + q * 4);
        float4 a = acc[q];
        a.x += bv.x; a.y += bv.y; a.z += bv.z; a.w += bv.w;
        if constexpr (ELU) {
            a.x = fast_elu(a.x); a.y = fast_elu(a.y);
            a.z = fast_elu(a.z); a.w = fast_elu(a.w);
        }
        *reinterpret_cast<float4*>(orow + q * 4) = a;
    }
}

// ---------------- conv0 v5: CIN=3, COUT=32, registers only + swizzle ----------------
__global__ __launch_bounds__(256) void conv0_v5(const float* __restrict__ x,
                                                const int* __restrict__ idx,
                                                const float* __restrict__ Wt,   // (27,32)
                                                const float* __restrict__ bias,
                                                float* __restrict__ out,
                                                int N, int GX) {
    int bx, b;
    swz_decode(blockIdx.x, GX, bx, b);
    const int v = bx * 256 + threadIdx.x;
    const float* __restrict__ xb = x + (size_t)b * N * 3;

    int nb[9];
    #pragma unroll
    for (int s = 0; s < 9; ++s) nb[s] = idx[(size_t)v * 9 + s];

    float g[27];
    #pragma unroll
    for (int s = 0; s < 9; ++s) {
        const float* __restrict__ p = xb + (size_t)nb[s] * 3;
        g[s * 3 + 0] = p[0]; g[s * 3 + 1] = p[1]; g[s * 3 + 2] = p[2];
    }

    float acc[32];
    #pragma unroll
    for (int c = 0; c < 32; ++c) acc[c] = bias[c];

    #pragma unroll
    for (int k = 0; k < 27; ++k) {
        const float gk = g[k];
        const float* __restrict__ wr = Wt + k * 32;
        #pragma unroll
        for (int c = 0; c < 32; ++c) acc[c] += gk * wr[c];
    }

    float* __restrict__ o = out + ((size_t)b * N + v) * 32;
    #pragma unroll
    for (int q = 0; q < 8; ++q) {
        float4 t;
        t.x = fast_elu(acc[q * 4 + 0]);
        t.y = fast_elu(acc[q * 4 + 1]);
        t.z = fast_elu(acc[q * 4 + 2]);
        t.w = fast_elu(acc[q * 4 + 3]);
        *reinterpret_cast<float4*>(o + q * 4) = t;
    }
}

// ---------------- out conv v4: CIN=32, COUT=3 — direct L2 reads, no LDS ----------------
__global__ __launch_bounds__(256, 4) void out_conv_v4(const float* __restrict__ x,
                                                      const int* __restrict__ idx,
                                                      const float* __restrict__ W,   // (3,288)
                                                      const float* __restrict__ bias,
                                                      float* __restrict__ out,
                                                      int N, int GX) {
    int bx, b;
    swz_decode(blockIdx.x, GX, bx, b);
    const int v = bx * 256 + threadIdx.x;
    const float* __restrict__ xb = x + (size_t)b * N * 32;

    int nb[9];
    #pragma unroll
    for (int s = 0; s < 9; ++s) nb[s] = idx[(size_t)v * 9 + s];

    float a0 = 0.f, a1 = 0.f, a2 = 0.f;
    #pragma unroll
    for (int s = 0; s < 9; ++s) {
        const float* __restrict__ xs = xb + (size_t)nb[s] * 32;
        #pragma unroll
        for (int q = 0; q < 8; ++q) {
            const float4 xv = *reinterpret_cast<const float4*>(xs + q * 4);
            const float4 w0 = *reinterpret_cast<const float4*>(W +   0 + s * 32 + q * 4);
            const float4 w1 = *reinterpret_cast<const float4*>(W + 288 + s * 32 + q * 4);
            const float4 w2 = *reinterpret_cast<const float4*>(W + 576 + s * 32 + q * 4);
            a0 += xv.x * w0.x + xv.y * w0.y + xv.z * w0.z + xv.w * w0.w;
            a1 += xv.x * w1.x + xv.y * w1.y + xv.z * w1.z + xv.w * w1.w;
            a2 += xv.x * w2.x + xv.y * w2.y + xv.z * w2.z + xv.w * w2.w;
        }
    }

    float* __restrict__ o = out + ((size_t)b * N + v) * 3;
    o[0] = a0 + bias[0]; o[1] = a1 + bias[1]; o[2] = a2 + bias[2];
}

// ---------------- pool v2: batch->XCD pinned; exact divisibility assumed ----------------
// out[b,r,:] = sum_{j<3} val[3r+j] * x[b, col[3r+j], :]
template<int C>
__global__ __launch_bounds__(256) void pool_v2(const float* __restrict__ x,
                                               const int* __restrict__ col,
                                               const float* __restrict__ val,
                                               float* __restrict__ out,
                                               int Nout, int Nin, int bpb) {
    constexpr int CQ = C / 4;
    const int id  = blockIdx.x;          // grid = bpb * 16
    const int xcd = id & 7;
    const int jj  = id >> 3;             // 0 .. 2*bpb-1
    const int hf  = (jj >= bpb) ? 1 : 0;
    const int inner = jj - (hf ? bpb : 0);
    const int b   = xcd + 8 * hf;

    const int t  = inner * 256 + threadIdx.x;   // within-batch flat id
    const int cq = t % CQ;
    const int r  = t / CQ;

    float ax = 0.f, ay = 0.f, az = 0.f, aw = 0.f;
    #pragma unroll
    for (int j = 0; j < 3; ++j) {
        const int   c0 = col[3 * r + j];
        const float vl = val[3 * r + j];
        const float4 xv = *reinterpret_cast<const float4*>(
            x + ((size_t)b * Nin + c0) * C + cq * 4);
        ax += vl * xv.x; ay += vl * xv.y; az += vl * xv.z; aw += vl * xv.w;
    }
    float4 o; o.x = ax; o.y = ay; o.z = az; o.w = aw;
    *reinterpret_cast<float4*>(out + ((size_t)b * Nout + r) * C + cq * 4) = o;
}

// ---------------- encoder FC: z = sigmoid(h @ fcW^T + fcb), h (16,8192) ----------------
__global__ __launch_bounds__(256) void fc_enc_kernel(const float* __restrict__ h,
                                                     const float* __restrict__ W,   // (256, 8192)
                                                     const float* __restrict__ bias,
                                                     float* __restrict__ z,
                                                     float* __restrict__ out_z,
                                                     float* __restrict__ out_mu) {
    const int l = blockIdx.x;
    const float* __restrict__ wr = W + (size_t)l * 8192;
    float acc[BATCH];
    #pragma unroll
    for (int b = 0; b < BATCH; ++b) acc[b] = 0.f;
    for (int k = threadIdx.x * 4; k < 8192; k += 256 * 4) {
        const float4 w4 = *reinterpret_cast<const float4*>(wr + k);
        #pragma unroll
        for (int b = 0; b < BATCH; ++b) {
            const float4 h4 = *reinterpret_cast<const float4*>(h + (size_t)b * 8192 + k);
            acc[b] += w4.x * h4.x + w4.y * h4.y + w4.z * h4.z + w4.w * h4.w;
        }
    }
    __shared__ float red[BATCH][4];
    const int wid = threadIdx.x >> 6, lane = threadIdx.x & 63;
    #pragma unroll
    for (int b = 0; b < BATCH; ++b) {
        float v = acc[b];
        for (int off = 32; off; off >>= 1) v += __shfl_down(v, off);
        if (lane == 0) red[b][wid] = v;
    }
    __syncthreads();
    if (threadIdx.x < BATCH) {
        const int b = threadIdx.x;
        float s = red[b][0] + red[b][1] + red[b][2] + red[b][3] + bias[l];
        s = 1.f / (1.f + expf(-s));
        z[b * 256 + l]      = s;
        out_z[b * 256 + l]  = s;
        out_mu[b * 256 + l] = s;
    }
}

// ---------------- decoder FC: h = z @ dfcW^T + dfcb -> (16, 8192) ----------------
__global__ __launch_bounds__(256) void fc_dec_kernel(const float* __restrict__ z,   // (16,256)
                                                     const float* __restrict__ W,   // (8192,256)
                                                     const float* __restrict__ bias,
                                                     float* __restrict__ out) {     // (16,8192)
    __shared__ float zl[BATCH * 256];
    for (int t = threadIdx.x; t < BATCH * 256; t += 256) zl[t] = z[t];
    __syncthreads();
    const int m = blockIdx.x * 256 + threadIdx.x;
    const float* __restrict__ wr = W + (size_t)m * 256;
    float acc[BATCH];
    #pragma unroll
    for (int b = 0; b < BATCH; ++b) acc[b] = 0.f;
    for (int l = 0; l < 256; l += 4) {
        const float4 w4 = *reinterpret_cast<const float4*>(wr + l);
        #pragma unroll
        for (int b = 0; b < BATCH; ++b) {
            acc[b] += w4.x * zl[b * 256 + l]     + w4.y * zl[b * 256 + l + 1]
                    + w4.z * zl[b * 256 + l + 2] + w4.w * zl[b * 256 + l + 3];
        }
    }
    const float bm = bias[m];
    #pragma unroll
    for (int b = 0; b < BATCH; ++b) out[(size_t)b * 8192 + m] = acc[b] + bm;
}

// ---------------- host-side orchestration ----------------
extern "C" void kernel_launch(void* const* d_in, const int* in_sizes, int n_in,
                              void* d_out, int out_size, void* d_ws, size_t ws_size,
                              hipStream_t stream) {
    (void)in_sizes; (void)n_in; (void)out_size; (void)ws_size;

    const float* x = (const float*)d_in[0];
    const int* si[4] = {(const int*)d_in[1], (const int*)d_in[2],
                        (const int*)d_in[3], (const int*)d_in[4]};
    const int*   dcol[4]; const float* dval[4];
    const int*   ucol[4]; const float* uval[4];
    for (int i = 0; i < 4; ++i) {
        dcol[i] = (const int*)  d_in[5 + 6 * i + 1];
        dval[i] = (const float*)d_in[5 + 6 * i + 2];
        ucol[i] = (const int*)  d_in[5 + 6 * i + 4];
        uval[i] = (const float*)d_in[5 + 6 * i + 5];
    }
    const float *enW[4], *enb[4], *deW[4], *deb[4];
    for (int i = 0; i < 4; ++i) {
        enW[i] = (const float*)d_in[29 + 2 * i];
        enb[i] = (const float*)d_in[30 + 2 * i];
        deW[i] = (const float*)d_in[41 + 2 * i];
        deb[i] = (const float*)d_in[42 + 2 * i];
    }
    const float* fcW  = (const float*)d_in[37];
    const float* fcb  = (const float*)d_in[38];
    const float* dfcW = (const float*)d_in[39];
    const float* dfcb = (const float*)d_in[40];
    const float* outW = (const float*)d_in[49];
    const float* outb = (const float*)d_in[50];

    // workspace layout (floats): A | Bb | z | transposed weights
    float* ws = (float*)d_ws;
    float* A  = ws;
    float* Bb = A  + (size_t)BATCH * NN0 * 32;
    float* z  = Bb + (size_t)BATCH * NN0 * 32;
    float* wt_en0 = z + BATCH * 256;
    float* wt_en1 = wt_en0 + 27  * 32;
    float* wt_en2 = wt_en1 + 288 * 32;
    float* wt_en3 = wt_en2 + 288 * 32;
    float* wt_de0 = wt_en3 + 288 * 64;
    float* wt_de1 = wt_de0 + 576 * 64;
    float* wt_de2 = wt_de1 + 576 * 32;
    float* wt_de3 = wt_de2 + 288 * 32;

    float* out    = (float*)d_out;                    // (16, 32768, 3)
    float* out_z  = out + (size_t)BATCH * NN0 * 3;    // (16, 256)
    float* out_mu = out_z + BATCH * 256;              // (16, 256)

    {
        TA ta; int off = 0;
        auto add = [&](int j, const float* W, float* Wt, int CO, int K) {
            ta.d[j] = TD{W, Wt, CO, K, off}; off += CO * K;
        };
        add(0, enW[0], wt_en0, 32, 27);
        add(1, enW[1], wt_en1, 32, 288);
        add(2, enW[2], wt_en2, 32, 288);
        add(3, enW[3], wt_en3, 64, 288);
        add(4, deW[0], wt_de0, 64, 576);
        add(5, deW[1], wt_de1, 32, 576);
        add(6, deW[2], wt_de2, 32, 288);
        add(7, deW[3], wt_de3, 32, 288);
        ta.total = off;
        transpose_all<<<(off + 255) / 256, 256, 0, stream>>>(ta);
    }

    auto pool32 = [&](const float* in, const int* col, const float* val,
                      float* o, int Nout, int Nin) {
        const int bpb = Nout * 8 / 256;
        pool_v2<32><<<bpb * BATCH, 256, 0, stream>>>(in, col, val, o, Nout, Nin, bpb);
    };
    auto pool64 = [&](const float* in, const int* col, const float* val,
                      float* o, int Nout, int Nin) {
        const int bpb = Nout * 16 / 256;
        pool_v2<64><<<bpb * BATCH, 256, 0, stream>>>(in, col, val, o, Nout, Nin, bpb);
    };

    // ---------------- encoder ----------------
    conv0_v5<<<(NN0 / 256) * BATCH, 256, 0, stream>>>(x, si[0], wt_en0, enb[0], A, NN0, NN0 / 256);
    pool32(A, dcol[0], dval[0], Bb, NN1, NN0);
    conv_v5<32, 32, true><<<(NN1 / 128) * BATCH, 256, 0, stream>>>(Bb, si[1], wt_en1, enb[1], A, NN1, NN1 / 128);
    pool32(A, dcol[1], dval[1], Bb, NN2, NN1);
    conv_v5<32, 32, true><<<(NN2 / 128) * BATCH, 256, 0, stream>>>(Bb, si[2], wt_en2, enb[2], A, NN2, NN2 / 128);
    pool32(A, dcol[2], dval[2], Bb, NN3, NN2);
    conv_v5<32, 64, true><<<(NN3 / 64) * BATCH, 256, 0, stream>>>(Bb, si[3], wt_en3, enb[3], A, NN3, NN3 / 64);
    pool64(A, dcol[3], dval[3], Bb, NN4, NN3);

    // ---------------- latent ----------------
    fc_enc_kernel<<<256, 256, 0, stream>>>(Bb, fcW, fcb, z, out_z, out_mu);
    fc_dec_kernel<<<32, 256, 0, stream>>>(z, dfcW, dfcb, A);

    // ---------------- decoder ----------------
    pool64(A, ucol[3], uval[3], Bb, NN3, NN4);
    conv_v5<64, 64, true><<<(NN3 / 64) * BATCH, 256, 0, stream>>>(Bb, si[3], wt_de0, deb[0], A, NN3, NN3 / 64);
    pool64(A, ucol[2], uval[2], Bb, NN2, NN3);
    conv_v5<64, 32, true><<<(NN2 / 128) * BATCH, 256, 0, stream>>>(Bb, si[2], wt_de1, deb[1], A, NN2, NN2 / 128);
    pool32(A, ucol[1], uval[1], Bb, NN1, NN2);
    conv_v5<32, 32, true><<<(NN1 / 128) * BATCH, 256, 0, stream>>>(Bb, si[1], wt_de2, deb[2], A, NN1, NN1 / 128);
    pool32(A, ucol[0], uval[0], Bb, NN0, NN1);
    conv_v5<32, 32, true><<<(NN0 / 128) * BATCH, 256, 0, stream>>>(Bb, si[0], wt_de3, deb[3], A, NN0, NN0 / 128);

    // ---------------- output head ----------------
    out_conv_v4<<<(NN0 / 256) * BATCH, 256, 0, stream>>>(A, si[0], outW, outb, out, NN0, NN0 / 256);
}

// Round 7
// 744.757 us; speedup vs baseline: 1.9682x; 1.9682x over previous
//
#include <hip/hip_runtime.h>
#include <cstdint>
#include <cstddef>

#define BATCH 16

static constexpr int NN0 = 32768, NN1 = 8192, NN2 = 2048, NN3 = 512, NN4 = 128;

__device__ __forceinline__ float fast_elu(float a) {
    return a > 0.f ? a : __expf(a) - 1.f;
}

// ---------------- fused weight transposes: W (CO,K) -> Wt (K,CO) ----------------
struct TD { const float* W; float* Wt; int CO, K, off; };
struct TA { TD d[8]; int total; };

__global__ __launch_bounds__(256) void transpose_all(TA a) {
    int i = blockIdx.x * 256 + threadIdx.x;
    if (i >= a.total) return;
    #pragma unroll
    for (int j = 0; j < 8; ++j) {
        const TD t = a.d[j];
        if (i >= t.off && i < t.off + t.CO * t.K) {
            int e = i - t.off, c = e / t.K, k = e - c * t.K;
            t.Wt[k * t.CO + c] = t.W[e];
            return;
        }
    }
}

// XCD-pinned swizzle for (GX, BATCH) grids launched as 1D GX*16:
// batch -> XCD (id&7); two sequential halves give batches {xcd, xcd+8}.
__device__ __forceinline__ void swz_decode(int id, int GX, int& bx, int& b) {
    const int xcd = id & 7;
    const int j   = id >> 3;
    const int hf  = (j >= GX) ? 1 : 0;
    bx = j - (hf ? GX : 0);
    b  = xcd + 8 * hf;
}

// async global->LDS, 16B per lane; lds base must be wave-uniform
#define GLD_LDS16(GA, LP) \
    __builtin_amdgcn_global_load_lds( \
        (const __attribute__((address_space(1))) void*)(GA), \
        (__attribute__((address_space(3))) void*)(LP), 16, 0, 0)

// ---------------- conv v6: async global_load_lds double-buffer, XOR-swizzled LDS ----
// x: (B,N,CIN), idx: (N,9), Wt: (9*CIN, COUT), out: (B,N,COUT)
// lane=vertex, wave=16-channel group; W via wave-uniform scalar loads.
template<int CIN, int COUT, bool ELU>
__global__ __launch_bounds__(256) void conv_v6(const float* __restrict__ x,
                                               const int* __restrict__ idx,
                                               const float* __restrict__ Wt,
                                               const float* __restrict__ bias,
                                               float* __restrict__ out,
                                               int N, int GX) {
    static_assert(COUT % 16 == 0, "COUT multiple of 16");
    constexpr int QG    = COUT / 16;
    static_assert(QG <= 4 && 4 % QG == 0, "QG in {1,2,4}");
    constexpr int VSETS = 4 / QG;
    constexpr int VPB   = 64 * VSETS;
    constexpr int CQ    = CIN / 4;            // float4 quads per row
    constexpr int BUFQ  = VPB * CQ;           // quads per buffer (linear, no pad)
    constexpr int GP    = BUFQ / 256;         // issue slots per thread
    static_assert(BUFQ % 256 == 0, "staging divisibility");

    __shared__ float4 g[2][BUFQ];
    __shared__ int    nbr[VPB][9];

    int bx, b;
    swz_decode(blockIdx.x, GX, bx, b);
    const int v0 = bx * VPB;
    const float* __restrict__ xb = x + (size_t)b * N * CIN;

    for (int t = threadIdx.x; t < VPB * 9; t += 256)
        nbr[t / 9][t % 9] = idx[(size_t)v0 * 9 + t];
    __syncthreads();                          // nbr ready for staging reads

    const int wv   = __builtin_amdgcn_readfirstlane(threadIdx.x >> 6);
    const int lane = threadIdx.x & 63;
    const int vset = wv / QG;
    const int qg   = wv % QG;
    const int vloc = vset * 64 + lane;
    const int vx7  = vloc & 7;                // read-side XOR (quad granules)

    // stage neighbor s into buffer `buf`: LDS linear in slot; source quad XOR-permuted
    // so that LDS[v][qpos] holds global quad (qpos ^ (v&7)).
    auto stage = [&](int s, int buf) {
        #pragma unroll
        for (int p = 0; p < GP; ++p) {
            const int slot  = p * 256 + threadIdx.x;
            const int v     = slot / CQ;
            const int qpos  = slot % CQ;
            const int qsrc  = qpos ^ (v & 7);
            const float* ga = xb + (size_t)nbr[v][s] * CIN + qsrc * 4;
            // wave-uniform LDS base; HW adds lane*16
            float4* lp = &g[buf][p * 256 + wv * 64];
            GLD_LDS16(ga, lp);
        }
    };

    float4 acc[4];
    #pragma unroll
    for (int q = 0; q < 4; ++q) acc[q] = make_float4(0.f, 0.f, 0.f, 0.f);

    stage(0, 0);
    __syncthreads();                          // drains vmcnt -> buf0 ready

    for (int s = 0; s < 9; ++s) {
        const int cur = s & 1;
        if (s < 8) stage(s + 1, cur ^ 1);     // async, lands during compute
        const float* __restrict__ wbase = Wt + (size_t)s * CIN * COUT + qg * 16;
        #pragma unroll
        for (int k4 = 0; k4 < CQ; ++k4) {
            const float4 gv = g[cur][vloc * CQ + (k4 ^ vx7)];
            #pragma unroll
            for (int kk = 0; kk < 4; ++kk) {
                const float* __restrict__ wr = wbase + (size_t)(k4 * 4 + kk) * COUT;
                const float4 w0 = *reinterpret_cast<const float4*>(wr);
                const float4 w1 = *reinterpret_cast<const float4*>(wr + 4);
                const float4 w2 = *reinterpret_cast<const float4*>(wr + 8);
                const float4 w3 = *reinterpret_cast<const float4*>(wr + 12);
                const float gk = (kk == 0) ? gv.x : (kk == 1) ? gv.y : (kk == 2) ? gv.z : gv.w;
                acc[0].x += gk * w0.x; acc[0].y += gk * w0.y; acc[0].z += gk * w0.z; acc[0].w += gk * w0.w;
                acc[1].x += gk * w1.x; acc[1].y += gk * w1.y; acc[1].z += gk * w1.z; acc[1].w += gk * w1.w;
                acc[2].x += gk * w2.x; acc[2].y += gk * w2.y; acc[2].z += gk * w2.z; acc[2].w += gk * w2.w;
                acc[3].x += gk * w3.x; acc[3].y += gk * w3.y; acc[3].z += gk * w3.z; acc[3].w += gk * w3.w;
            }
        }
        __syncthreads();   // all reads of g[cur] done; vmcnt(0) drained -> g[cur^1] ready
    }

    float* __restrict__ orow = out + ((size_t)b * N + v0 + vloc) * COUT + qg * 16;
    #pragma unroll
    for (int q = 0; q < 4; ++q) {
        const float4 bv = *reinterpret_cast<const float4*>(bias + qg * 16 + q * 4);
        float4 a = acc[q];
        a.x += bv.x; a.y += bv.y; a.z += bv.z; a.w += bv.w;
        if constexpr (ELU) {
            a.x = fast_elu(a.x); a.y = fast_elu(a.y);
            a.z = fast_elu(a.z); a.w = fast_elu(a.w);
        }
        *reinterpret_cast<float4*>(orow + q * 4) = a;
    }
}

// ---------------- conv0 v5: CIN=3, COUT=32, registers only + swizzle ----------------
__global__ __launch_bounds__(256) void conv0_v5(const float* __restrict__ x,
                                                const int* __restrict__ idx,
                                                const float* __restrict__ Wt,   // (27,32)
                                                const float* __restrict__ bias,
                                                float* __restrict__ out,
                                                int N, int GX) {
    int bx, b;
    swz_decode(blockIdx.x, GX, bx, b);
    const int v = bx * 256 + threadIdx.x;
    const float* __restrict__ xb = x + (size_t)b * N * 3;

    int nb[9];
    #pragma unroll
    for (int s = 0; s < 9; ++s) nb[s] = idx[(size_t)v * 9 + s];

    float g[27];
    #pragma unroll
    for (int s = 0; s < 9; ++s) {
        const float* __restrict__ p = xb + (size_t)nb[s] * 3;
        g[s * 3 + 0] = p[0]; g[s * 3 + 1] = p[1]; g[s * 3 + 2] = p[2];
    }

    float acc[32];
    #pragma unroll
    for (int c = 0; c < 32; ++c) acc[c] = bias[c];

    #pragma unroll
    for (int k = 0; k < 27; ++k) {
        const float gk = g[k];
        const float* __restrict__ wr = Wt + k * 32;
        #pragma unroll
        for (int c = 0; c < 32; ++c) acc[c] += gk * wr[c];
    }

    float* __restrict__ o = out + ((size_t)b * N + v) * 32;
    #pragma unroll
    for (int q = 0; q < 8; ++q) {
        float4 t;
        t.x = fast_elu(acc[q * 4 + 0]);
        t.y = fast_elu(acc[q * 4 + 1]);
        t.z = fast_elu(acc[q * 4 + 2]);
        t.w = fast_elu(acc[q * 4 + 3]);
        *reinterpret_cast<float4*>(o + q * 4) = t;
    }
}

// ---------------- out conv v4: CIN=32, COUT=3 — direct L2 reads, no LDS ----------------
__global__ __launch_bounds__(256, 4) void out_conv_v4(const float* __restrict__ x,
                                                      const int* __restrict__ idx,
                                                      const float* __restrict__ W,   // (3,288)
                                                      const float* __restrict__ bias,
                                                      float* __restrict__ out,
                                                      int N, int GX) {
    int bx, b;
    swz_decode(blockIdx.x, GX, bx, b);
    const int v = bx * 256 + threadIdx.x;
    const float* __restrict__ xb = x + (size_t)b * N * 32;

    int nb[9];
    #pragma unroll
    for (int s = 0; s < 9; ++s) nb[s] = idx[(size_t)v * 9 + s];

    float a0 = 0.f, a1 = 0.f, a2 = 0.f;
    #pragma unroll
    for (int s = 0; s < 9; ++s) {
        const float* __restrict__ xs = xb + (size_t)nb[s] * 32;
        #pragma unroll
        for (int q = 0; q < 8; ++q) {
            const float4 xv = *reinterpret_cast<const float4*>(xs + q * 4);
            const float4 w0 = *reinterpret_cast<const float4*>(W +   0 + s * 32 + q * 4);
            const float4 w1 = *reinterpret_cast<const float4*>(W + 288 + s * 32 + q * 4);
            const float4 w2 = *reinterpret_cast<const float4*>(W + 576 + s * 32 + q * 4);
            a0 += xv.x * w0.x + xv.y * w0.y + xv.z * w0.z + xv.w * w0.w;
            a1 += xv.x * w1.x + xv.y * w1.y + xv.z * w1.z + xv.w * w1.w;
            a2 += xv.x * w2.x + xv.y * w2.y + xv.z * w2.z + xv.w * w2.w;
        }
    }

    float* __restrict__ o = out + ((size_t)b * N + v) * 3;
    o[0] = a0 + bias[0]; o[1] = a1 + bias[1]; o[2] = a2 + bias[2];
}

// ---------------- pool v2: batch->XCD pinned ----------------
template<int C>
__global__ __launch_bounds__(256) void pool_v2(const float* __restrict__ x,
                                               const int* __restrict__ col,
                                               const float* __restrict__ val,
                                               float* __restrict__ out,
                                               int Nout, int Nin, int bpb) {
    constexpr int CQ = C / 4;
    const int id  = blockIdx.x;
    const int xcd = id & 7;
    const int jj  = id >> 3;
    const int hf  = (jj >= bpb) ? 1 : 0;
    const int inner = jj - (hf ? bpb : 0);
    const int b   = xcd + 8 * hf;

    const int t  = inner * 256 + threadIdx.x;
    const int cq = t % CQ;
    const int r  = t / CQ;

    float ax = 0.f, ay = 0.f, az = 0.f, aw = 0.f;
    #pragma unroll
    for (int j = 0; j < 3; ++j) {
        const int   c0 = col[3 * r + j];
        const float vl = val[3 * r + j];
        const float4 xv = *reinterpret_cast<const float4*>(
            x + ((size_t)b * Nin + c0) * C + cq * 4);
        ax += vl * xv.x; ay += vl * xv.y; az += vl * xv.z; aw += vl * xv.w;
    }
    float4 o; o.x = ax; o.y = ay; o.z = az; o.w = aw;
    *reinterpret_cast<float4*>(out + ((size_t)b * Nout + r) * C + cq * 4) = o;
}

// ---------------- encoder FC: z = sigmoid(h @ fcW^T + fcb), h (16,8192) ----------------
__global__ __launch_bounds__(256) void fc_enc_kernel(const float* __restrict__ h,
                                                     const float* __restrict__ W,   // (256, 8192)
                                                     const float* __restrict__ bias,
                                                     float* __restrict__ z,
                                                     float* __restrict__ out_z,
                                                     float* __restrict__ out_mu) {
    const int l = blockIdx.x;
    const float* __restrict__ wr = W + (size_t)l * 8192;
    float acc[BATCH];
    #pragma unroll
    for (int b = 0; b < BATCH; ++b) acc[b] = 0.f;
    for (int k = threadIdx.x * 4; k < 8192; k += 256 * 4) {
        const float4 w4 = *reinterpret_cast<const float4*>(wr + k);
        #pragma unroll
        for (int b = 0; b < BATCH; ++b) {
            const float4 h4 = *reinterpret_cast<const float4*>(h + (size_t)b * 8192 + k);
            acc[b] += w4.x * h4.x + w4.y * h4.y + w4.z * h4.z + w4.w * h4.w;
        }
    }
    __shared__ float red[BATCH][4];
    const int wid = threadIdx.x >> 6, lane = threadIdx.x & 63;
    #pragma unroll
    for (int b = 0; b < BATCH; ++b) {
        float v = acc[b];
        for (int off = 32; off; off >>= 1) v += __shfl_down(v, off);
        if (lane == 0) red[b][wid] = v;
    }
    __syncthreads();
    if (threadIdx.x < BATCH) {
        const int b = threadIdx.x;
        float s = red[b][0] + red[b][1] + red[b][2] + red[b][3] + bias[l];
        s = 1.f / (1.f + expf(-s));
        z[b * 256 + l]      = s;
        out_z[b * 256 + l]  = s;
        out_mu[b * 256 + l] = s;
    }
}

// ---------------- decoder FC: h = z @ dfcW^T + dfcb -> (16, 8192) ----------------
__global__ __launch_bounds__(256) void fc_dec_kernel(const float* __restrict__ z,   // (16,256)
                                                     const float* __restrict__ W,   // (8192,256)
                                                     const float* __restrict__ bias,
                                                     float* __restrict__ out) {     // (16,8192)
    __shared__ float zl[BATCH * 256];
    for (int t = threadIdx.x; t < BATCH * 256; t += 256) zl[t] = z[t];
    __syncthreads();
    const int m = blockIdx.x * 256 + threadIdx.x;
    const float* __restrict__ wr = W + (size_t)m * 256;
    float acc[BATCH];
    #pragma unroll
    for (int b = 0; b < BATCH; ++b) acc[b] = 0.f;
    for (int l = 0; l < 256; l += 4) {
        const float4 w4 = *reinterpret_cast<const float4*>(wr + l);
        #pragma unroll
        for (int b = 0; b < BATCH; ++b) {
            acc[b] += w4.x * zl[b * 256 + l]     + w4.y * zl[b * 256 + l + 1]
                    + w4.z * zl[b * 256 + l + 2] + w4.w * zl[b * 256 + l + 3];
        }
    }
    const float bm = bias[m];
    #pragma unroll
    for (int b = 0; b < BATCH; ++b) out[(size_t)b * 8192 + m] = acc[b] + bm;
}

// ---------------- host-side orchestration ----------------
extern "C" void kernel_launch(void* const* d_in, const int* in_sizes, int n_in,
                              void* d_out, int out_size, void* d_ws, size_t ws_size,
                              hipStream_t stream) {
    (void)in_sizes; (void)n_in; (void)out_size; (void)ws_size;

    const float* x = (const float*)d_in[0];
    const int* si[4] = {(const int*)d_in[1], (const int*)d_in[2],
                        (const int*)d_in[3], (const int*)d_in[4]};
    const int*   dcol[4]; const float* dval[4];
    const int*   ucol[4]; const float* uval[4];
    for (int i = 0; i < 4; ++i) {
        dcol[i] = (const int*)  d_in[5 + 6 * i + 1];
        dval[i] = (const float*)d_in[5 + 6 * i + 2];
        ucol[i] = (const int*)  d_in[5 + 6 * i + 4];
        uval[i] = (const float*)d_in[5 + 6 * i + 5];
    }
    const float *enW[4], *enb[4], *deW[4], *deb[4];
    for (int i = 0; i < 4; ++i) {
        enW[i] = (const float*)d_in[29 + 2 * i];
        enb[i] = (const float*)d_in[30 + 2 * i];
        deW[i] = (const float*)d_in[41 + 2 * i];
        deb[i] = (const float*)d_in[42 + 2 * i];
    }
    const float* fcW  = (const float*)d_in[37];
    const float* fcb  = (const float*)d_in[38];
    const float* dfcW = (const float*)d_in[39];
    const float* dfcb = (const float*)d_in[40];
    const float* outW = (const float*)d_in[49];
    const float* outb = (const float*)d_in[50];

    // workspace layout (floats): A | Bb | z | transposed weights
    float* ws = (float*)d_ws;
    float* A  = ws;
    float* Bb = A  + (size_t)BATCH * NN0 * 32;
    float* z  = Bb + (size_t)BATCH * NN0 * 32;
    float* wt_en0 = z + BATCH * 256;
    float* wt_en1 = wt_en0 + 27  * 32;
    float* wt_en2 = wt_en1 + 288 * 32;
    float* wt_en3 = wt_en2 + 288 * 32;
    float* wt_de0 = wt_en3 + 288 * 64;
    float* wt_de1 = wt_de0 + 576 * 64;
    float* wt_de2 = wt_de1 + 576 * 32;
    float* wt_de3 = wt_de2 + 288 * 32;

    float* out    = (float*)d_out;                    // (16, 32768, 3)
    float* out_z  = out + (size_t)BATCH * NN0 * 3;    // (16, 256)
    float* out_mu = out_z + BATCH * 256;              // (16, 256)

    {
        TA ta; int off = 0;
        auto add = [&](int j, const float* W, float* Wt, int CO, int K) {
            ta.d[j] = TD{W, Wt, CO, K, off}; off += CO * K;
        };
        add(0, enW[0], wt_en0, 32, 27);
        add(1, enW[1], wt_en1, 32, 288);
        add(2, enW[2], wt_en2, 32, 288);
        add(3, enW[3], wt_en3, 64, 288);
        add(4, deW[0], wt_de0, 64, 576);
        add(5, deW[1], wt_de1, 32, 576);
        add(6, deW[2], wt_de2, 32, 288);
        add(7, deW[3], wt_de3, 32, 288);
        ta.total = off;
        transpose_all<<<(off + 255) / 256, 256, 0, stream>>>(ta);
    }

    auto pool32 = [&](const float* in, const int* col, const float* val,
                      float* o, int Nout, int Nin) {
        const int bpb = Nout * 8 / 256;
        pool_v2<32><<<bpb * BATCH, 256, 0, stream>>>(in, col, val, o, Nout, Nin, bpb);
    };
    auto pool64 = [&](const float* in, const int* col, const float* val,
                      float* o, int Nout, int Nin) {
        const int bpb = Nout * 16 / 256;
        pool_v2<64><<<bpb * BATCH, 256, 0, stream>>>(in, col, val, o, Nout, Nin, bpb);
    };

    // ---------------- encoder ----------------
    conv0_v5<<<(NN0 / 256) * BATCH, 256, 0, stream>>>(x, si[0], wt_en0, enb[0], A, NN0, NN0 / 256);
    pool32(A, dcol[0], dval[0], Bb, NN1, NN0);
    conv_v6<32, 32, true><<<(NN1 / 128) * BATCH, 256, 0, stream>>>(Bb, si[1], wt_en1, enb[1], A, NN1, NN1 / 128);
    pool32(A, dcol[1], dval[1], Bb, NN2, NN1);
    conv_v6<32, 32, true><<<(NN2 / 128) * BATCH, 256, 0, stream>>>(Bb, si[2], wt_en2, enb[2], A, NN2, NN2 / 128);
    pool32(A, dcol[2], dval[2], Bb, NN3, NN2);
    conv_v6<32, 64, true><<<(NN3 / 64) * BATCH, 256, 0, stream>>>(Bb, si[3], wt_en3, enb[3], A, NN3, NN3 / 64);
    pool64(A, dcol[3], dval[3], Bb, NN4, NN3);

    // ---------------- latent ----------------
    fc_enc_kernel<<<256, 256, 0, stream>>>(Bb, fcW, fcb, z, out_z, out_mu);
    fc_dec_kernel<<<32, 256, 0, stream>>>(z, dfcW, dfcb, A);

    // ---------------- decoder ----------------
    pool64(A, ucol[3], uval[3], Bb, NN3, NN4);
    conv_v6<64, 64, true><<<(NN3 / 64) * BATCH, 256, 0, stream>>>(Bb, si[3], wt_de0, deb[0], A, NN3, NN3 / 64);
    pool64(A, ucol[2], uval[2], Bb, NN2, NN3);
    conv_v6<64, 32, true><<<(NN2 / 128) * BATCH, 256, 0, stream>>>(Bb, si[2], wt_de1, deb[1], A, NN2, NN2 / 128);
    pool32(A, ucol[1], uval[1], Bb, NN1, NN2);
    conv_v6<32, 32, true><<<(NN1 / 128) * BATCH, 256, 0, stream>>>(Bb, si[1], wt_de2, deb[2], A, NN1, NN1 / 128);
    pool32(A, ucol[0], uval[0], Bb, NN0, NN1);
    conv_v6<32, 32, true><<<(NN0 / 128) * BATCH, 256, 0, stream>>>(Bb, si[0], wt_de3, deb[3], A, NN0, NN0 / 128);

    // ---------------- output head ----------------
    out_conv_v4<<<(NN0 / 256) * BATCH, 256, 0, stream>>>(A, si[0], outW, outb, out, NN0, NN0 / 256);
}

// Round 8
// 727.649 us; speedup vs baseline: 2.0145x; 1.0235x over previous
//
#include <hip/hip_runtime.h>
#include <cstdint>
#include <cstddef>

#define BATCH 16

static constexpr int NN0 = 32768, NN1 = 8192, NN2 = 2048, NN3 = 512, NN4 = 128;

__device__ __forceinline__ float fast_elu(float a) {
    return a > 0.f ? a : __expf(a) - 1.f;
}

// ---------------- fused weight transposes: W (CO,K) -> Wt (K,CO) ----------------
struct TD { const float* W; float* Wt; int CO, K, off; };
struct TA { TD d[8]; int total; };

__global__ __launch_bounds__(256) void transpose_all(TA a) {
    int i = blockIdx.x * 256 + threadIdx.x;
    if (i >= a.total) return;
    #pragma unroll
    for (int j = 0; j < 8; ++j) {
        const TD t = a.d[j];
        if (i >= t.off && i < t.off + t.CO * t.K) {
            int e = i - t.off, c = e / t.K, k = e - c * t.K;
            t.Wt[k * t.CO + c] = t.W[e];
            return;
        }
    }
}

// XCD-pinned swizzle for (GX, BATCH) grids launched as 1D GX*16:
// batch -> XCD (id&7); two sequential halves give batches {xcd, xcd+8}.
__device__ __forceinline__ void swz_decode(int id, int GX, int& bx, int& b) {
    const int xcd = id & 7;
    const int j   = id >> 3;
    const int hf  = (j >= GX) ? 1 : 0;
    bx = j - (hf ? GX : 0);
    b  = xcd + 8 * hf;
}

// async global->LDS, 16B per lane; lds base must be wave-uniform
#define GLD_LDS16(GA, LP) \
    __builtin_amdgcn_global_load_lds( \
        (const __attribute__((address_space(1))) void*)(GA), \
        (__attribute__((address_space(3))) void*)(LP), 16, 0, 0)

// ---------------- conv v7: single-buffer global_load_lds, rotation-swizzled LDS ----
// x: (B,N,CIN), idx: (N,9), Wt: (9*CIN, COUT), out: (B,N,COUT)
// lane=vertex, wave=16-channel group; W via wave-uniform scalar loads.
// LDS row v holds quads rotated by (v&7): position qpos stores global quad
// (qpos&~7)|((qpos+v)&7). Read of quad k4 -> position (k4&~7)|((k4-v)&7),
// whose bank group rotates with lane (R2/R4-proven conflict-free pattern).
template<int CIN, int COUT, bool ELU>
__global__ __launch_bounds__(256) void conv_v7(const float* __restrict__ x,
                                               const int* __restrict__ idx,
                                               const float* __restrict__ Wt,
                                               const float* __restrict__ bias,
                                               float* __restrict__ out,
                                               int N, int GX) {
    static_assert(COUT % 16 == 0, "COUT multiple of 16");
    constexpr int QG    = COUT / 16;
    static_assert(QG <= 4 && 4 % QG == 0, "QG in {1,2,4}");
    constexpr int VSETS = 4 / QG;
    constexpr int VPB   = 64 * VSETS;
    constexpr int CQ    = CIN / 4;            // float4 quads per row
    constexpr int BUFQ  = VPB * CQ;           // quads in buffer (linear)
    constexpr int GP    = BUFQ / 256;         // DMA issues per thread
    static_assert(BUFQ % 256 == 0, "staging divisibility");

    __shared__ float4 g[BUFQ];
    __shared__ int    nbr[VPB][9];

    int bx, b;
    swz_decode(blockIdx.x, GX, bx, b);
    const int v0 = bx * VPB;
    const float* __restrict__ xb = x + (size_t)b * N * CIN;

    for (int t = threadIdx.x; t < VPB * 9; t += 256)
        nbr[t / 9][t % 9] = idx[(size_t)v0 * 9 + t];

    const int wv   = __builtin_amdgcn_readfirstlane(threadIdx.x >> 6);
    const int lane = threadIdx.x & 63;
    const int vset = wv / QG;
    const int qg   = wv % QG;
    const int vloc = vset * 64 + lane;
    const int vx7  = vloc & 7;

    auto stage = [&](int s) {
        #pragma unroll
        for (int p = 0; p < GP; ++p) {
            const int slot = p * 256 + threadIdx.x;
            const int v    = slot / CQ;
            const int qpos = slot % CQ;
            const int qsrc = (qpos & ~7) | ((qpos + (v & 7)) & 7);
            const float* ga = xb + (size_t)nbr[v][s] * CIN + qsrc * 4;
            GLD_LDS16(ga, &g[p * 256 + wv * 64]);   // wave-uniform base; HW adds lane*16
        }
    };

    float4 acc[4];
    #pragma unroll
    for (int q = 0; q < 4; ++q) acc[q] = make_float4(0.f, 0.f, 0.f, 0.f);

    __syncthreads();                          // nbr ready

    for (int s = 0; s < 9; ++s) {
        stage(s);
        __syncthreads();                      // vmcnt(0) drained -> buffer ready
        const float* __restrict__ wbase = Wt + (size_t)s * CIN * COUT + qg * 16;
        #pragma unroll
        for (int k4 = 0; k4 < CQ; ++k4) {
            const float4 gv = g[vloc * CQ + ((k4 & ~7) | ((k4 - vx7) & 7))];
            #pragma unroll
            for (int kk = 0; kk < 4; ++kk) {
                const float* __restrict__ wr = wbase + (size_t)(k4 * 4 + kk) * COUT;
                const float4 w0 = *reinterpret_cast<const float4*>(wr);
                const float4 w1 = *reinterpret_cast<const float4*>(wr + 4);
                const float4 w2 = *reinterpret_cast<const float4*>(wr + 8);
                const float4 w3 = *reinterpret_cast<const float4*>(wr + 12);
                const float gk = (kk == 0) ? gv.x : (kk == 1) ? gv.y : (kk == 2) ? gv.z : gv.w;
                acc[0].x += gk * w0.x; acc[0].y += gk * w0.y; acc[0].z += gk * w0.z; acc[0].w += gk * w0.w;
                acc[1].x += gk * w1.x; acc[1].y += gk * w1.y; acc[1].z += gk * w1.z; acc[1].w += gk * w1.w;
                acc[2].x += gk * w2.x; acc[2].y += gk * w2.y; acc[2].z += gk * w2.z; acc[2].w += gk * w2.w;
                acc[3].x += gk * w3.x; acc[3].y += gk * w3.y; acc[3].z += gk * w3.z; acc[3].w += gk * w3.w;
            }
        }
        __syncthreads();                      // reads done before next overwrite
    }

    float* __restrict__ orow = out + ((size_t)b * N + v0 + vloc) * COUT + qg * 16;
    #pragma unroll
    for (int q = 0; q < 4; ++q) {
        const float4 bv = *reinterpret_cast<const float4*>(bias + qg * 16 + q * 4);
        float4 a = acc[q];
        a.x += bv.x; a.y += bv.y; a.z += bv.z; a.w += bv.w;
        if constexpr (ELU) {
            a.x = fast_elu(a.x); a.y = fast_elu(a.y);
            a.z = fast_elu(a.z); a.w = fast_elu(a.w);
        }
        *reinterpret_cast<float4*>(orow + q * 4) = a;
    }
}

// ---------------- conv0 v5: CIN=3, COUT=32, registers only + swizzle ----------------
__global__ __launch_bounds__(256) void conv0_v5(const float* __restrict__ x,
                                                const int* __restrict__ idx,
                                                const float* __restrict__ Wt,   // (27,32)
                                                const float* __restrict__ bias,
                                                float* __restrict__ out,
                                                int N, int GX) {
    int bx, b;
    swz_decode(blockIdx.x, GX, bx, b);
    const int v = bx * 256 + threadIdx.x;
    const float* __restrict__ xb = x + (size_t)b * N * 3;

    int nb[9];
    #pragma unroll
    for (int s = 0; s < 9; ++s) nb[s] = idx[(size_t)v * 9 + s];

    float g[27];
    #pragma unroll
    for (int s = 0; s < 9; ++s) {
        const float* __restrict__ p = xb + (size_t)nb[s] * 3;
        g[s * 3 + 0] = p[0]; g[s * 3 + 1] = p[1]; g[s * 3 + 2] = p[2];
    }

    float acc[32];
    #pragma unroll
    for (int c = 0; c < 32; ++c) acc[c] = bias[c];

    #pragma unroll
    for (int k = 0; k < 27; ++k) {
        const float gk = g[k];
        const float* __restrict__ wr = Wt + k * 32;
        #pragma unroll
        for (int c = 0; c < 32; ++c) acc[c] += gk * wr[c];
    }

    float* __restrict__ o = out + ((size_t)b * N + v) * 32;
    #pragma unroll
    for (int q = 0; q < 8; ++q) {
        float4 t;
        t.x = fast_elu(acc[q * 4 + 0]);
        t.y = fast_elu(acc[q * 4 + 1]);
        t.z = fast_elu(acc[q * 4 + 2]);
        t.w = fast_elu(acc[q * 4 + 3]);
        *reinterpret_cast<float4*>(o + q * 4) = t;
    }
}

// ---------------- out conv v4: CIN=32, COUT=3 — direct L2 reads, no LDS ----------------
__global__ __launch_bounds__(256, 4) void out_conv_v4(const float* __restrict__ x,
                                                      const int* __restrict__ idx,
                                                      const float* __restrict__ W,   // (3,288)
                                                      const float* __restrict__ bias,
                                                      float* __restrict__ out,
                                                      int N, int GX) {
    int bx, b;
    swz_decode(blockIdx.x, GX, bx, b);
    const int v = bx * 256 + threadIdx.x;
    const float* __restrict__ xb = x + (size_t)b * N * 32;

    int nb[9];
    #pragma unroll
    for (int s = 0; s < 9; ++s) nb[s] = idx[(size_t)v * 9 + s];

    float a0 = 0.f, a1 = 0.f, a2 = 0.f;
    #pragma unroll
    for (int s = 0; s < 9; ++s) {
        const float* __restrict__ xs = xb + (size_t)nb[s] * 32;
        #pragma unroll
        for (int q = 0; q < 8; ++q) {
            const float4 xv = *reinterpret_cast<const float4*>(xs + q * 4);
            const float4 w0 = *reinterpret_cast<const float4*>(W +   0 + s * 32 + q * 4);
            const float4 w1 = *reinterpret_cast<const float4*>(W + 288 + s * 32 + q * 4);
            const float4 w2 = *reinterpret_cast<const float4*>(W + 576 + s * 32 + q * 4);
            a0 += xv.x * w0.x + xv.y * w0.y + xv.z * w0.z + xv.w * w0.w;
            a1 += xv.x * w1.x + xv.y * w1.y + xv.z * w1.z + xv.w * w1.w;
            a2 += xv.x * w2.x + xv.y * w2.y + xv.z * w2.z + xv.w * w2.w;
        }
    }

    float* __restrict__ o = out + ((size_t)b * N + v) * 3;
    o[0] = a0 + bias[0]; o[1] = a1 + bias[1]; o[2] = a2 + bias[2];
}

// ---------------- pool v2: batch->XCD pinned ----------------
template<int C>
__global__ __launch_bounds__(256) void pool_v2(const float* __restrict__ x,
                                               const int* __restrict__ col,
                                               const float* __restrict__ val,
                                               float* __restrict__ out,
                                               int Nout, int Nin, int bpb) {
    constexpr int CQ = C / 4;
    const int id  = blockIdx.x;
    const int xcd = id & 7;
    const int jj  = id >> 3;
    const int hf  = (jj >= bpb) ? 1 : 0;
    const int inner = jj - (hf ? bpb : 0);
    const int b   = xcd + 8 * hf;

    const int t  = inner * 256 + threadIdx.x;
    const int cq = t % CQ;
    const int r  = t / CQ;

    float ax = 0.f, ay = 0.f, az = 0.f, aw = 0.f;
    #pragma unroll
    for (int j = 0; j < 3; ++j) {
        const int   c0 = col[3 * r + j];
        const float vl = val[3 * r + j];
        const float4 xv = *reinterpret_cast<const float4*>(
            x + ((size_t)b * Nin + c0) * C + cq * 4);
        ax += vl * xv.x; ay += vl * xv.y; az += vl * xv.z; aw += vl * xv.w;
    }
    float4 o; o.x = ax; o.y = ay; o.z = az; o.w = aw;
    *reinterpret_cast<float4*>(out + ((size_t)b * Nout + r) * C + cq * 4) = o;
}

// ---------------- encoder FC: z = sigmoid(h @ fcW^T + fcb), h (16,8192) ----------------
__global__ __launch_bounds__(256) void fc_enc_kernel(const float* __restrict__ h,
                                                     const float* __restrict__ W,   // (256, 8192)
                                                     const float* __restrict__ bias,
                                                     float* __restrict__ z,
                                                     float* __restrict__ out_z,
                                                     float* __restrict__ out_mu) {
    const int l = blockIdx.x;
    const float* __restrict__ wr = W + (size_t)l * 8192;
    float acc[BATCH];
    #pragma unroll
    for (int b = 0; b < BATCH; ++b) acc[b] = 0.f;
    for (int k = threadIdx.x * 4; k < 8192; k += 256 * 4) {
        const float4 w4 = *reinterpret_cast<const float4*>(wr + k);
        #pragma unroll
        for (int b = 0; b < BATCH; ++b) {
            const float4 h4 = *reinterpret_cast<const float4*>(h + (size_t)b * 8192 + k);
            acc[b] += w4.x * h4.x + w4.y * h4.y + w4.z * h4.z + w4.w * h4.w;
        }
    }
    __shared__ float red[BATCH][4];
    const int wid = threadIdx.x >> 6, lane = threadIdx.x & 63;
    #pragma unroll
    for (int b = 0; b < BATCH; ++b) {
        float v = acc[b];
        for (int off = 32; off; off >>= 1) v += __shfl_down(v, off);
        if (lane == 0) red[b][wid] = v;
    }
    __syncthreads();
    if (threadIdx.x < BATCH) {
        const int b = threadIdx.x;
        float s = red[b][0] + red[b][1] + red[b][2] + red[b][3] + bias[l];
        s = 1.f / (1.f + expf(-s));
        z[b * 256 + l]      = s;
        out_z[b * 256 + l]  = s;
        out_mu[b * 256 + l] = s;
    }
}

// ---------------- decoder FC: h = z @ dfcW^T + dfcb -> (16, 8192) ----------------
__global__ __launch_bounds__(256) void fc_dec_kernel(const float* __restrict__ z,   // (16,256)
                                                     const float* __restrict__ W,   // (8192,256)
                                                     const float* __restrict__ bias,
                                                     float* __restrict__ out) {     // (16,8192)
    __shared__ float zl[BATCH * 256];
    for (int t = threadIdx.x; t < BATCH * 256; t += 256) zl[t] = z[t];
    __syncthreads();
    const int m = blockIdx.x * 256 + threadIdx.x;
    const float* __restrict__ wr = W + (size_t)m * 256;
    float acc[BATCH];
    #pragma unroll
    for (int b = 0; b < BATCH; ++b) acc[b] = 0.f;
    for (int l = 0; l < 256; l += 4) {
        const float4 w4 = *reinterpret_cast<const float4*>(wr + l);
        #pragma unroll
        for (int b = 0; b < BATCH; ++b) {
            acc[b] += w4.x * zl[b * 256 + l]     + w4.y * zl[b * 256 + l + 1]
                    + w4.z * zl[b * 256 + l + 2] + w4.w * zl[b * 256 + l + 3];
        }
    }
    const float bm = bias[m];
    #pragma unroll
    for (int b = 0; b < BATCH; ++b) out[(size_t)b * 8192 + m] = acc[b] + bm;
}

// ---------------- host-side orchestration ----------------
extern "C" void kernel_launch(void* const* d_in, const int* in_sizes, int n_in,
                              void* d_out, int out_size, void* d_ws, size_t ws_size,
                              hipStream_t stream) {
    (void)in_sizes; (void)n_in; (void)out_size; (void)ws_size;

    const float* x = (const float*)d_in[0];
    const int* si[4] = {(const int*)d_in[1], (const int*)d_in[2],
                        (const int*)d_in[3], (const int*)d_in[4]};
    const int*   dcol[4]; const float* dval[4];
    const int*   ucol[4]; const float* uval[4];
    for (int i = 0; i < 4; ++i) {
        dcol[i] = (const int*)  d_in[5 + 6 * i + 1];
        dval[i] = (const float*)d_in[5 + 6 * i + 2];
        ucol[i] = (const int*)  d_in[5 + 6 * i + 4];
        uval[i] = (const float*)d_in[5 + 6 * i + 5];
    }
    const float *enW[4], *enb[4], *deW[4], *deb[4];
    for (int i = 0; i < 4; ++i) {
        enW[i] = (const float*)d_in[29 + 2 * i];
        enb[i] = (const float*)d_in[30 + 2 * i];
        deW[i] = (const float*)d_in[41 + 2 * i];
        deb[i] = (const float*)d_in[42 + 2 * i];
    }
    const float* fcW  = (const float*)d_in[37];
    const float* fcb  = (const float*)d_in[38];
    const float* dfcW = (const float*)d_in[39];
    const float* dfcb = (const float*)d_in[40];
    const float* outW = (const float*)d_in[49];
    const float* outb = (const float*)d_in[50];

    // workspace layout (floats): A | Bb | z | transposed weights
    float* ws = (float*)d_ws;
    float* A  = ws;
    float* Bb = A  + (size_t)BATCH * NN0 * 32;
    float* z  = Bb + (size_t)BATCH * NN0 * 32;
    float* wt_en0 = z + BATCH * 256;
    float* wt_en1 = wt_en0 + 27  * 32;
    float* wt_en2 = wt_en1 + 288 * 32;
    float* wt_en3 = wt_en2 + 288 * 32;
    float* wt_de0 = wt_en3 + 288 * 64;
    float* wt_de1 = wt_de0 + 576 * 64;
    float* wt_de2 = wt_de1 + 576 * 32;
    float* wt_de3 = wt_de2 + 288 * 32;

    float* out    = (float*)d_out;                    // (16, 32768, 3)
    float* out_z  = out + (size_t)BATCH * NN0 * 3;    // (16, 256)
    float* out_mu = out_z + BATCH * 256;              // (16, 256)

    {
        TA ta; int off = 0;
        auto add = [&](int j, const float* W, float* Wt, int CO, int K) {
            ta.d[j] = TD{W, Wt, CO, K, off}; off += CO * K;
        };
        add(0, enW[0], wt_en0, 32, 27);
        add(1, enW[1], wt_en1, 32, 288);
        add(2, enW[2], wt_en2, 32, 288);
        add(3, enW[3], wt_en3, 64, 288);
        add(4, deW[0], wt_de0, 64, 576);
        add(5, deW[1], wt_de1, 32, 576);
        add(6, deW[2], wt_de2, 32, 288);
        add(7, deW[3], wt_de3, 32, 288);
        ta.total = off;
        transpose_all<<<(off + 255) / 256, 256, 0, stream>>>(ta);
    }

    auto pool32 = [&](const float* in, const int* col, const float* val,
                      float* o, int Nout, int Nin) {
        const int bpb = Nout * 8 / 256;
        pool_v2<32><<<bpb * BATCH, 256, 0, stream>>>(in, col, val, o, Nout, Nin, bpb);
    };
    auto pool64 = [&](const float* in, const int* col, const float* val,
                      float* o, int Nout, int Nin) {
        const int bpb = Nout * 16 / 256;
        pool_v2<64><<<bpb * BATCH, 256, 0, stream>>>(in, col, val, o, Nout, Nin, bpb);
    };

    // ---------------- encoder ----------------
    conv0_v5<<<(NN0 / 256) * BATCH, 256, 0, stream>>>(x, si[0], wt_en0, enb[0], A, NN0, NN0 / 256);
    pool32(A, dcol[0], dval[0], Bb, NN1, NN0);
    conv_v7<32, 32, true><<<(NN1 / 128) * BATCH, 256, 0, stream>>>(Bb, si[1], wt_en1, enb[1], A, NN1, NN1 / 128);
    pool32(A, dcol[1], dval[1], Bb, NN2, NN1);
    conv_v7<32, 32, true><<<(NN2 / 128) * BATCH, 256, 0, stream>>>(Bb, si[2], wt_en2, enb[2], A, NN2, NN2 / 128);
    pool32(A, dcol[2], dval[2], Bb, NN3, NN2);
    conv_v7<32, 64, true><<<(NN3 / 64) * BATCH, 256, 0, stream>>>(Bb, si[3], wt_en3, enb[3], A, NN3, NN3 / 64);
    pool64(A, dcol[3], dval[3], Bb, NN4, NN3);

    // ---------------- latent ----------------
    fc_enc_kernel<<<256, 256, 0, stream>>>(Bb, fcW, fcb, z, out_z, out_mu);
    fc_dec_kernel<<<32, 256, 0, stream>>>(z, dfcW, dfcb, A);

    // ---------------- decoder ----------------
    pool64(A, ucol[3], uval[3], Bb, NN3, NN4);
    conv_v7<64, 64, true><<<(NN3 / 64) * BATCH, 256, 0, stream>>>(Bb, si[3], wt_de0, deb[0], A, NN3, NN3 / 64);
    pool64(A, ucol[2], uval[2], Bb, NN2, NN3);
    conv_v7<64, 32, true><<<(NN2 / 128) * BATCH, 256, 0, stream>>>(Bb, si[2], wt_de1, deb[1], A, NN2, NN2 / 128);
    pool32(A, ucol[1], uval[1], Bb, NN1, NN2);
    conv_v7<32, 32, true><<<(NN1 / 128) * BATCH, 256, 0, stream>>>(Bb, si[1], wt_de2, deb[2], A, NN1, NN1 / 128);
    pool32(A, ucol[0], uval[0], Bb, NN0, NN1);
    conv_v7<32, 32, true><<<(NN0 / 128) * BATCH, 256, 0, stream>>>(Bb, si[0], wt_de3, deb[3], A, NN0, NN0 / 128);

    // ---------------- output head ----------------
    out_conv_v4<<<(NN0 / 256) * BATCH, 256, 0, stream>>>(A, si[0], outW, outb, out, NN0, NN0 / 256);
}